// Round 2
// baseline (337.919 us; speedup 1.0000x reference)
//
#include <hip/hip_runtime.h>

// PaDiM training-branch accumulation + finalize.
// embeddings: [B=32, C=192, P=3136] f32
// means:      [P, C] f32 (running sums)
// covariances:[P, C, C] f32 (running outer-product sums)
// n:          int scalar (96)
// out: learned_means [P,C] ++ learned_covs [P,C,C]
//
// R2: single-pass 12x12 register micro-tile per thread (16x16 threads cover
// the full 192x192 cov). LDS:FMA instruction ratio 6 ds_read_b128 : 144 FMA
// (was 2:16) -- R1 was serialized on LDS issue (~141us of ds_read_b128/CU).

#define BB 32
#define CC 192
#define PP 3136
#define EPSV 0.01f

__global__ __launch_bounds__(256, 2) void padim_kernel(
    const float* __restrict__ emb,    // [B,C,P]
    const float* __restrict__ means,  // [P,C]
    const float* __restrict__ covs,   // [P,C,C]
    const int*   __restrict__ n_ptr,  // [1]
    float* __restrict__ out_means,    // [P,C]
    float* __restrict__ out_covs)     // [P,C,C]
{
    __shared__ __align__(16) float E[BB][CC];   // rows 768B -> float4 aligned
    __shared__ __align__(16) float m[CC];

    // XCD-aware swizzle: XCD x owns contiguous 392 patches -> emb cache-line
    // reuse (16 consecutive p per 64B line) stays within one XCD's L2.
    const int bid = blockIdx.x;
    const int p = (bid & 7) * (PP / 8) + (bid >> 3);
    const int t = threadIdx.x;

    const float n_new = (float)(n_ptr[0] + BB);       // 128
    const float inv_nnew = 1.0f / n_new;
    const float inv_nm1 = 1.0f / (n_new - 1.0f);      // 1/127

    // ---- Stage E[b][c] = emb[b, c, p] (strided gather; L2 absorbs reuse) ----
    #pragma unroll
    for (int i = t; i < BB * CC; i += 256) {
        const int b = i / CC;
        const int c = i - b * CC;
        E[b][c] = emb[(size_t)i * PP + p];
    }
    __syncthreads();

    // ---- Means ----
    if (t < CC) {
        float s = 0.0f;
        #pragma unroll
        for (int b = 0; b < BB; ++b) s += E[b][t];
        const float mm = (means[(size_t)p * CC + t] + s) * inv_nnew;
        m[t] = mm;
        out_means[(size_t)p * CC + t] = mm;
    }
    __syncthreads();

    // ---- Full 192x192 cov in one pass: thread (ty,tx) owns rows c0..c0+11,
    //      cols d0..d0+11. acc = 144 VGPR; ~200 total -> 2 waves/SIMD. ----
    const int tx = t & 15;
    const int ty = t >> 4;
    const int c0 = ty * 12;   // 48B-aligned -> float4 ok
    const int d0 = tx * 12;

    float acc[12][12];
    #pragma unroll
    for (int i = 0; i < 12; ++i)
        #pragma unroll
        for (int j = 0; j < 12; ++j) acc[i][j] = 0.f;

    #pragma unroll 2
    for (int b = 0; b < BB; ++b) {
        float cs[12], ds[12];
        // cs: 4 distinct addrs/wave (broadcast). ds: tx & tx+8 share banks
        // at different addrs -> 2-way aliasing (free, m136).
        *reinterpret_cast<float4*>(&cs[0]) = *reinterpret_cast<const float4*>(&E[b][c0]);
        *reinterpret_cast<float4*>(&cs[4]) = *reinterpret_cast<const float4*>(&E[b][c0 + 4]);
        *reinterpret_cast<float4*>(&cs[8]) = *reinterpret_cast<const float4*>(&E[b][c0 + 8]);
        *reinterpret_cast<float4*>(&ds[0]) = *reinterpret_cast<const float4*>(&E[b][d0]);
        *reinterpret_cast<float4*>(&ds[4]) = *reinterpret_cast<const float4*>(&E[b][d0 + 4]);
        *reinterpret_cast<float4*>(&ds[8]) = *reinterpret_cast<const float4*>(&E[b][d0 + 8]);
        #pragma unroll
        for (int i = 0; i < 12; ++i)
            #pragma unroll
            for (int j = 0; j < 12; ++j)
                acc[i][j] = fmaf(cs[i], ds[j], acc[i][j]);
    }

    // ---- Fused finalize + stream cov (read-modify-write, one pass) ----
    float mc[12], md[12];
    *reinterpret_cast<float4*>(&mc[0]) = *reinterpret_cast<const float4*>(&m[c0]);
    *reinterpret_cast<float4*>(&mc[4]) = *reinterpret_cast<const float4*>(&m[c0 + 4]);
    *reinterpret_cast<float4*>(&mc[8]) = *reinterpret_cast<const float4*>(&m[c0 + 8]);
    *reinterpret_cast<float4*>(&md[0]) = *reinterpret_cast<const float4*>(&m[d0]);
    *reinterpret_cast<float4*>(&md[4]) = *reinterpret_cast<const float4*>(&m[d0 + 4]);
    *reinterpret_cast<float4*>(&md[8]) = *reinterpret_cast<const float4*>(&m[d0 + 8]);

    const float* __restrict__ cov_p = covs + (size_t)p * CC * CC;
    float* __restrict__ out_p = out_covs + (size_t)p * CC * CC;

    #pragma unroll
    for (int i = 0; i < 12; ++i) {
        const size_t row = (size_t)(c0 + i) * CC + d0;
        const float4 cin0 = *reinterpret_cast<const float4*>(&cov_p[row]);
        const float4 cin1 = *reinterpret_cast<const float4*>(&cov_p[row + 4]);
        const float4 cin2 = *reinterpret_cast<const float4*>(&cov_p[row + 8]);
        const float nmc = n_new * mc[i];
        float4 o0, o1, o2;
        o0.x = (cin0.x + acc[i][0]  - nmc * md[0])  * inv_nm1;
        o0.y = (cin0.y + acc[i][1]  - nmc * md[1])  * inv_nm1;
        o0.z = (cin0.z + acc[i][2]  - nmc * md[2])  * inv_nm1;
        o0.w = (cin0.w + acc[i][3]  - nmc * md[3])  * inv_nm1;
        o1.x = (cin1.x + acc[i][4]  - nmc * md[4])  * inv_nm1;
        o1.y = (cin1.y + acc[i][5]  - nmc * md[5])  * inv_nm1;
        o1.z = (cin1.z + acc[i][6]  - nmc * md[6])  * inv_nm1;
        o1.w = (cin1.w + acc[i][7]  - nmc * md[7])  * inv_nm1;
        o2.x = (cin2.x + acc[i][8]  - nmc * md[8])  * inv_nm1;
        o2.y = (cin2.y + acc[i][9]  - nmc * md[9])  * inv_nm1;
        o2.z = (cin2.z + acc[i][10] - nmc * md[10]) * inv_nm1;
        o2.w = (cin2.w + acc[i][11] - nmc * md[11]) * inv_nm1;
        if (tx == ty) {
            // diagonal element j == i (compile-time after unroll)
            if (i == 0)  o0.x += EPSV;
            if (i == 1)  o0.y += EPSV;
            if (i == 2)  o0.z += EPSV;
            if (i == 3)  o0.w += EPSV;
            if (i == 4)  o1.x += EPSV;
            if (i == 5)  o1.y += EPSV;
            if (i == 6)  o1.z += EPSV;
            if (i == 7)  o1.w += EPSV;
            if (i == 8)  o2.x += EPSV;
            if (i == 9)  o2.y += EPSV;
            if (i == 10) o2.z += EPSV;
            if (i == 11) o2.w += EPSV;
        }
        *reinterpret_cast<float4*>(&out_p[row])     = o0;
        *reinterpret_cast<float4*>(&out_p[row + 4]) = o1;
        *reinterpret_cast<float4*>(&out_p[row + 8]) = o2;
    }
}

extern "C" void kernel_launch(void* const* d_in, const int* in_sizes, int n_in,
                              void* d_out, int out_size, void* d_ws, size_t ws_size,
                              hipStream_t stream) {
    const float* emb   = (const float*)d_in[0];
    const float* means = (const float*)d_in[1];
    const float* covs  = (const float*)d_in[2];
    const int*   n_ptr = (const int*)d_in[3];

    float* out_means = (float*)d_out;                      // [P,C]
    float* out_covs  = (float*)d_out + (size_t)PP * CC;    // [P,C,C]

    hipLaunchKernelGGL(padim_kernel, dim3(PP), dim3(256), 0, stream,
                       emb, means, covs, n_ptr, out_means, out_covs);
}

// Round 3
// 252.748 us; speedup vs baseline: 1.3370x; 1.3370x over previous
//
#include <hip/hip_runtime.h>

// PaDiM training-branch accumulation + finalize.
// embeddings: [B=32, C=192, P=3136] f32
// means:      [P, C] f32 (running sums)
// covariances:[P, C, C] f32 (running outer-product sums)
// n:          int scalar (96)
// out: learned_means [P,C] ++ learned_covs [P,C,C]
//
// R3: 6x12 micro-tile, 2 passes (acc=72 VGPR, ~130 total -> no spill at
// __launch_bounds__(256,3) cap=168). R2's 12x12 spilled (VGPR_Count=128,
// +76MB scratch WRITE traffic). LDS pipe: 3 b128 + 3 b64 per b-iter per
// thread feeding 72 FMAs -> ~70us/CU (was ~141us in R1), hides under the
// ~160us HBM stream floor. d-side columns are 3 disjoint 64-wide groups so
// every cov RMW instruction is a contiguous 256B wave segment.

#define BB 32
#define CC 192
#define PP 3136
#define EPSV 0.01f

__global__ __launch_bounds__(256, 3) void padim_kernel(
    const float* __restrict__ emb,    // [B,C,P]
    const float* __restrict__ means,  // [P,C]
    const float* __restrict__ covs,   // [P,C,C]
    const int*   __restrict__ n_ptr,  // [1]
    float* __restrict__ out_means,    // [P,C]
    float* __restrict__ out_covs)     // [P,C,C]
{
    __shared__ __align__(16) float E[BB][CC];   // 24.0 KB, rows 768B
    __shared__ __align__(16) float m[CC];       // 768 B

    // XCD-aware swizzle: XCD x owns contiguous 392 patches -> emb cache-line
    // reuse (16 consecutive p per 64B line) stays within one XCD's L2.
    const int bid = blockIdx.x;
    const int p = (bid & 7) * (PP / 8) + (bid >> 3);
    const int t = threadIdx.x;

    const float n_new = (float)(n_ptr[0] + BB);       // 128
    const float inv_nnew = 1.0f / n_new;
    const float inv_nm1 = 1.0f / (n_new - 1.0f);      // 1/127

    // ---- Stage E[b][c] = emb[b, c, p] (strided gather; L2 absorbs reuse) ----
    #pragma unroll
    for (int k = 0; k < (BB * CC) / 256; ++k) {
        const int i = t + k * 256;
        const int b = i / CC;
        const int c = i - b * CC;
        E[b][c] = emb[(size_t)i * PP + p];
    }
    __syncthreads();

    // ---- Means ----
    if (t < CC) {
        float s = 0.0f;
        #pragma unroll
        for (int b = 0; b < BB; ++b) s += E[b][t];
        const float mm = (means[(size_t)p * CC + t] + s) * inv_nnew;
        m[t] = mm;
        out_means[(size_t)p * CC + t] = mm;
    }
    __syncthreads();

    const int tx = t & 15;   // d dimension: 3 groups of cols g*64 + tx*4
    const int ty = t >> 4;   // c dimension: 6 rows, 2 passes of 96
    const int dbase0 = tx * 4;

    const float* __restrict__ cov_p = covs + (size_t)p * CC * CC;
    float* __restrict__ out_p = out_covs + (size_t)p * CC * CC;

    // d-side means (pass-invariant)
    float md[12];
    *reinterpret_cast<float4*>(&md[0]) = *reinterpret_cast<const float4*>(&m[dbase0]);
    *reinterpret_cast<float4*>(&md[4]) = *reinterpret_cast<const float4*>(&m[64 + dbase0]);
    *reinterpret_cast<float4*>(&md[8]) = *reinterpret_cast<const float4*>(&m[128 + dbase0]);

    #pragma unroll
    for (int pass = 0; pass < 2; ++pass) {
        const int c0 = pass * 96 + ty * 6;

        float acc[6][12];
        #pragma unroll
        for (int i = 0; i < 6; ++i)
            #pragma unroll
            for (int j = 0; j < 12; ++j) acc[i][j] = 0.f;

        #pragma unroll 4
        for (int b = 0; b < BB; ++b) {
            float cs[6], ds[12];
            // ds: lanes at 16B stride -> conflict-free, coalesced-style reads
            *reinterpret_cast<float4*>(&ds[0]) = *reinterpret_cast<const float4*>(&E[b][dbase0]);
            *reinterpret_cast<float4*>(&ds[4]) = *reinterpret_cast<const float4*>(&E[b][64 + dbase0]);
            *reinterpret_cast<float4*>(&ds[8]) = *reinterpret_cast<const float4*>(&E[b][128 + dbase0]);
            // cs: 8B loads, broadcast across the 16 tx lanes (4 addrs/wave)
            *reinterpret_cast<float2*>(&cs[0]) = *reinterpret_cast<const float2*>(&E[b][c0]);
            *reinterpret_cast<float2*>(&cs[2]) = *reinterpret_cast<const float2*>(&E[b][c0 + 2]);
            *reinterpret_cast<float2*>(&cs[4]) = *reinterpret_cast<const float2*>(&E[b][c0 + 4]);
            #pragma unroll
            for (int i = 0; i < 6; ++i)
                #pragma unroll
                for (int j = 0; j < 12; ++j)
                    acc[i][j] = fmaf(cs[i], ds[j], acc[i][j]);
        }

        // c-side means
        float mc[6];
        *reinterpret_cast<float2*>(&mc[0]) = *reinterpret_cast<const float2*>(&m[c0]);
        *reinterpret_cast<float2*>(&mc[2]) = *reinterpret_cast<const float2*>(&m[c0 + 2]);
        *reinterpret_cast<float2*>(&mc[4]) = *reinterpret_cast<const float2*>(&m[c0 + 4]);

        // ---- Fused finalize + cov RMW stream ----
        #pragma unroll
        for (int i = 0; i < 6; ++i) {
            const int c = c0 + i;
            const size_t row = (size_t)c * CC;
            const float nmc = n_new * mc[i];
            #pragma unroll
            for (int g = 0; g < 3; ++g) {
                const int db = g * 64 + dbase0;
                const float4 cin = *reinterpret_cast<const float4*>(&cov_p[row + db]);
                float4 o;
                o.x = (cin.x + acc[i][g*4+0] - nmc * md[g*4+0]) * inv_nm1;
                o.y = (cin.y + acc[i][g*4+1] - nmc * md[g*4+1]) * inv_nm1;
                o.z = (cin.z + acc[i][g*4+2] - nmc * md[g*4+2]) * inv_nm1;
                o.w = (cin.w + acc[i][g*4+3] - nmc * md[g*4+3]) * inv_nm1;
                const int dd = c - db;   // diagonal hits when 0 <= dd < 4
                if (dd == 0) o.x += EPSV;
                if (dd == 1) o.y += EPSV;
                if (dd == 2) o.z += EPSV;
                if (dd == 3) o.w += EPSV;
                *reinterpret_cast<float4*>(&out_p[row + db]) = o;
            }
        }
    }
}

extern "C" void kernel_launch(void* const* d_in, const int* in_sizes, int n_in,
                              void* d_out, int out_size, void* d_ws, size_t ws_size,
                              hipStream_t stream) {
    const float* emb   = (const float*)d_in[0];
    const float* means = (const float*)d_in[1];
    const float* covs  = (const float*)d_in[2];
    const int*   n_ptr = (const int*)d_in[3];

    float* out_means = (float*)d_out;                      // [P,C]
    float* out_covs  = (float*)d_out + (size_t)PP * CC;    // [P,C,C]

    hipLaunchKernelGGL(padim_kernel, dim3(PP), dim3(256), 0, stream,
                       emb, means, covs, n_ptr, out_means, out_covs);
}

// Round 5
// 234.528 us; speedup vs baseline: 1.4408x; 1.0777x over previous
//
#include <hip/hip_runtime.h>

// PaDiM training-branch accumulation + finalize.
// embeddings: [B=32, C=192, P=3136] f32
// means:      [P, C] f32 (running sums)
// covariances:[P, C, C] f32 (running outer-product sums)
// n:          int scalar (96)
// out: learned_means [P,C] ++ learned_covs [P,C,C]
//
// R5 == R4 with the __builtin_nontemporal_store fix (native ext_vector_type
// instead of HIP_vector_type float4).
// Two-kernel pipeline: kernel 1 transposes emb into Et[p][b][c] (coalesced
// tiled 64x64 LDS transpose, ~154MB => ~35us); kernel 2 stages Et[p] with 6
// coalesced float4 loads/thread (Et 77MB fits L3). out_covs written with
// non-temporal stores (write-once stream; keep L3 for cov/Et).

#define BB 32
#define CC 192
#define PP 3136
#define II (BB * CC)   // 6144
#define EPSV 0.01f

typedef float nat_float4 __attribute__((ext_vector_type(4)));

// ---------- Kernel 1: tiled transpose emb [II][PP] -> Et [PP][II] ----------
__global__ __launch_bounds__(256) void transpose_kernel(
    const float* __restrict__ emb, float* __restrict__ Et)
{
    __shared__ float tile[64][65];          // +1 pad: conflict-free col reads
    const int i0 = blockIdx.x * 64;         // 96 tiles over II
    const int p0 = blockIdx.y * 64;         // 49 tiles over PP
    const int t = threadIdx.x;
    const int tc = t & 63;                  // fast index (coalesced)
    const int tr4 = t >> 6;                 // 0..3

    #pragma unroll
    for (int k = 0; k < 16; ++k) {
        const int r = k * 4 + tr4;          // i-local row
        tile[r][tc] = emb[(size_t)(i0 + r) * PP + (p0 + tc)];
    }
    __syncthreads();
    #pragma unroll
    for (int k = 0; k < 16; ++k) {
        const int r = k * 4 + tr4;          // p-local row
        Et[(size_t)(p0 + r) * II + (i0 + tc)] = tile[tc][r];
    }
}

// ---------- Kernel 2: per-patch SYRK + finalize (coalesced staging) ----------
__global__ __launch_bounds__(256, 3) void padim_main(
    const float* __restrict__ Et,     // [P][II] transposed embeddings
    const float* __restrict__ means,  // [P,C]
    const float* __restrict__ covs,   // [P,C,C]
    const int*   __restrict__ n_ptr,  // [1]
    float* __restrict__ out_means,    // [P,C]
    float* __restrict__ out_covs)     // [P,C,C]
{
    __shared__ __align__(16) float E[II];   // 24 KB, flat [b*CC + c]
    __shared__ __align__(16) float m[CC];

    const int p = blockIdx.x;
    const int t = threadIdx.x;

    const float n_new = (float)(n_ptr[0] + BB);       // 128
    const float inv_nnew = 1.0f / n_new;
    const float inv_nm1 = 1.0f / (n_new - 1.0f);      // 1/127

    // ---- Stage Et[p] -> LDS: 6 coalesced float4 per thread (1KB/wave-inst) ----
    {
        const float4* __restrict__ src = reinterpret_cast<const float4*>(Et + (size_t)p * II);
        float4* dst = reinterpret_cast<float4*>(E);
        #pragma unroll
        for (int k = 0; k < 6; ++k) dst[k * 256 + t] = src[k * 256 + t];
    }
    __syncthreads();

    // ---- Means ----
    if (t < CC) {
        float s = 0.0f;
        #pragma unroll
        for (int b = 0; b < BB; ++b) s += E[b * CC + t];
        const float mm = (means[(size_t)p * CC + t] + s) * inv_nnew;
        m[t] = mm;
        out_means[(size_t)p * CC + t] = mm;
    }
    __syncthreads();

    const int tx = t & 15;   // d: 3 groups of cols g*64 + tx*4
    const int ty = t >> 4;   // c: 6 rows, 2 passes of 96
    const int dbase0 = tx * 4;

    const float* __restrict__ cov_p = covs + (size_t)p * CC * CC;
    float* __restrict__ out_p = out_covs + (size_t)p * CC * CC;

    float md[12];
    *reinterpret_cast<float4*>(&md[0]) = *reinterpret_cast<const float4*>(&m[dbase0]);
    *reinterpret_cast<float4*>(&md[4]) = *reinterpret_cast<const float4*>(&m[64 + dbase0]);
    *reinterpret_cast<float4*>(&md[8]) = *reinterpret_cast<const float4*>(&m[128 + dbase0]);

    #pragma unroll
    for (int pass = 0; pass < 2; ++pass) {
        const int c0 = pass * 96 + ty * 6;

        float acc[6][12];
        #pragma unroll
        for (int i = 0; i < 6; ++i)
            #pragma unroll
            for (int j = 0; j < 12; ++j) acc[i][j] = 0.f;

        #pragma unroll 4
        for (int b = 0; b < BB; ++b) {
            const float* __restrict__ Eb = E + b * CC;
            float cs[6], ds[12];
            *reinterpret_cast<float4*>(&ds[0]) = *reinterpret_cast<const float4*>(&Eb[dbase0]);
            *reinterpret_cast<float4*>(&ds[4]) = *reinterpret_cast<const float4*>(&Eb[64 + dbase0]);
            *reinterpret_cast<float4*>(&ds[8]) = *reinterpret_cast<const float4*>(&Eb[128 + dbase0]);
            *reinterpret_cast<float2*>(&cs[0]) = *reinterpret_cast<const float2*>(&Eb[c0]);
            *reinterpret_cast<float2*>(&cs[2]) = *reinterpret_cast<const float2*>(&Eb[c0 + 2]);
            *reinterpret_cast<float2*>(&cs[4]) = *reinterpret_cast<const float2*>(&Eb[c0 + 4]);
            #pragma unroll
            for (int i = 0; i < 6; ++i)
                #pragma unroll
                for (int j = 0; j < 12; ++j)
                    acc[i][j] = fmaf(cs[i], ds[j], acc[i][j]);
        }

        float mc[6];
        *reinterpret_cast<float2*>(&mc[0]) = *reinterpret_cast<const float2*>(&m[c0]);
        *reinterpret_cast<float2*>(&mc[2]) = *reinterpret_cast<const float2*>(&m[c0 + 2]);
        *reinterpret_cast<float2*>(&mc[4]) = *reinterpret_cast<const float2*>(&m[c0 + 4]);

        #pragma unroll
        for (int i = 0; i < 6; ++i) {
            const int c = c0 + i;
            const size_t row = (size_t)c * CC;
            const float nmc = n_new * mc[i];
            #pragma unroll
            for (int g = 0; g < 3; ++g) {
                const int db = g * 64 + dbase0;
                const float4 cin = *reinterpret_cast<const float4*>(&cov_p[row + db]);
                nat_float4 o;
                o.x = (cin.x + acc[i][g*4+0] - nmc * md[g*4+0]) * inv_nm1;
                o.y = (cin.y + acc[i][g*4+1] - nmc * md[g*4+1]) * inv_nm1;
                o.z = (cin.z + acc[i][g*4+2] - nmc * md[g*4+2]) * inv_nm1;
                o.w = (cin.w + acc[i][g*4+3] - nmc * md[g*4+3]) * inv_nm1;
                const int dd = c - db;   // diagonal hits when 0 <= dd < 4
                if (dd == 0) o.x += EPSV;
                if (dd == 1) o.y += EPSV;
                if (dd == 2) o.z += EPSV;
                if (dd == 3) o.w += EPSV;
                __builtin_nontemporal_store(o, reinterpret_cast<nat_float4*>(&out_p[row + db]));
            }
        }
    }
}

// ---------- Fallback (ws too small): R3 single-kernel with direct gather ----
__global__ __launch_bounds__(256, 3) void padim_fallback(
    const float* __restrict__ emb, const float* __restrict__ means,
    const float* __restrict__ covs, const int* __restrict__ n_ptr,
    float* __restrict__ out_means, float* __restrict__ out_covs)
{
    __shared__ __align__(16) float E[II];
    __shared__ __align__(16) float m[CC];
    const int bid = blockIdx.x;
    const int p = (bid & 7) * (PP / 8) + (bid >> 3);
    const int t = threadIdx.x;
    const float n_new = (float)(n_ptr[0] + BB);
    const float inv_nnew = 1.0f / n_new;
    const float inv_nm1 = 1.0f / (n_new - 1.0f);
    #pragma unroll
    for (int k = 0; k < II / 256; ++k) {
        const int i = t + k * 256;
        E[i] = emb[(size_t)i * PP + p];
    }
    __syncthreads();
    if (t < CC) {
        float s = 0.0f;
        #pragma unroll
        for (int b = 0; b < BB; ++b) s += E[b * CC + t];
        const float mm = (means[(size_t)p * CC + t] + s) * inv_nnew;
        m[t] = mm;
        out_means[(size_t)p * CC + t] = mm;
    }
    __syncthreads();
    const int tx = t & 15, ty = t >> 4;
    const int dbase0 = tx * 4;
    const float* __restrict__ cov_p = covs + (size_t)p * CC * CC;
    float* __restrict__ out_p = out_covs + (size_t)p * CC * CC;
    float md[12];
    *reinterpret_cast<float4*>(&md[0]) = *reinterpret_cast<const float4*>(&m[dbase0]);
    *reinterpret_cast<float4*>(&md[4]) = *reinterpret_cast<const float4*>(&m[64 + dbase0]);
    *reinterpret_cast<float4*>(&md[8]) = *reinterpret_cast<const float4*>(&m[128 + dbase0]);
    #pragma unroll
    for (int pass = 0; pass < 2; ++pass) {
        const int c0 = pass * 96 + ty * 6;
        float acc[6][12];
        #pragma unroll
        for (int i = 0; i < 6; ++i)
            #pragma unroll
            for (int j = 0; j < 12; ++j) acc[i][j] = 0.f;
        #pragma unroll 4
        for (int b = 0; b < BB; ++b) {
            const float* __restrict__ Eb = E + b * CC;
            float cs[6], ds[12];
            *reinterpret_cast<float4*>(&ds[0]) = *reinterpret_cast<const float4*>(&Eb[dbase0]);
            *reinterpret_cast<float4*>(&ds[4]) = *reinterpret_cast<const float4*>(&Eb[64 + dbase0]);
            *reinterpret_cast<float4*>(&ds[8]) = *reinterpret_cast<const float4*>(&Eb[128 + dbase0]);
            *reinterpret_cast<float2*>(&cs[0]) = *reinterpret_cast<const float2*>(&Eb[c0]);
            *reinterpret_cast<float2*>(&cs[2]) = *reinterpret_cast<const float2*>(&Eb[c0 + 2]);
            *reinterpret_cast<float2*>(&cs[4]) = *reinterpret_cast<const float2*>(&Eb[c0 + 4]);
            #pragma unroll
            for (int i = 0; i < 6; ++i)
                #pragma unroll
                for (int j = 0; j < 12; ++j)
                    acc[i][j] = fmaf(cs[i], ds[j], acc[i][j]);
        }
        float mc[6];
        *reinterpret_cast<float2*>(&mc[0]) = *reinterpret_cast<const float2*>(&m[c0]);
        *reinterpret_cast<float2*>(&mc[2]) = *reinterpret_cast<const float2*>(&m[c0 + 2]);
        *reinterpret_cast<float2*>(&mc[4]) = *reinterpret_cast<const float2*>(&m[c0 + 4]);
        #pragma unroll
        for (int i = 0; i < 6; ++i) {
            const int c = c0 + i;
            const size_t row = (size_t)c * CC;
            const float nmc = n_new * mc[i];
            #pragma unroll
            for (int g = 0; g < 3; ++g) {
                const int db = g * 64 + dbase0;
                const float4 cin = *reinterpret_cast<const float4*>(&cov_p[row + db]);
                float4 o;
                o.x = (cin.x + acc[i][g*4+0] - nmc * md[g*4+0]) * inv_nm1;
                o.y = (cin.y + acc[i][g*4+1] - nmc * md[g*4+1]) * inv_nm1;
                o.z = (cin.z + acc[i][g*4+2] - nmc * md[g*4+2]) * inv_nm1;
                o.w = (cin.w + acc[i][g*4+3] - nmc * md[g*4+3]) * inv_nm1;
                const int dd = c - db;
                if (dd == 0) o.x += EPSV;
                if (dd == 1) o.y += EPSV;
                if (dd == 2) o.z += EPSV;
                if (dd == 3) o.w += EPSV;
                *reinterpret_cast<float4*>(&out_p[row + db]) = o;
            }
        }
    }
}

extern "C" void kernel_launch(void* const* d_in, const int* in_sizes, int n_in,
                              void* d_out, int out_size, void* d_ws, size_t ws_size,
                              hipStream_t stream) {
    const float* emb   = (const float*)d_in[0];
    const float* means = (const float*)d_in[1];
    const float* covs  = (const float*)d_in[2];
    const int*   n_ptr = (const int*)d_in[3];

    float* out_means = (float*)d_out;                      // [P,C]
    float* out_covs  = (float*)d_out + (size_t)PP * CC;    // [P,C,C]

    const size_t et_bytes = (size_t)PP * II * sizeof(float);   // 77.1 MB
    if (ws_size >= et_bytes) {
        float* Et = (float*)d_ws;
        hipLaunchKernelGGL(transpose_kernel, dim3(II / 64, PP / 64), dim3(256),
                           0, stream, emb, Et);
        hipLaunchKernelGGL(padim_main, dim3(PP), dim3(256), 0, stream,
                           Et, means, covs, n_ptr, out_means, out_covs);
    } else {
        hipLaunchKernelGGL(padim_fallback, dim3(PP), dim3(256), 0, stream,
                           emb, means, covs, n_ptr, out_means, out_covs);
    }
}

// Round 6
// 215.673 us; speedup vs baseline: 1.5668x; 1.0874x over previous
//
#include <hip/hip_runtime.h>

// PaDiM training-branch accumulation + finalize.
// embeddings: [B=32, C=192, P=3136] f32
// means:      [P, C] f32 (running sums)
// covariances:[P, C, C] f32 (running outer-product sums)
// n:          int scalar (96)
// out: learned_means [P,C] ++ learned_covs [P,C,C]
//
// R6: slab-split main kernel. R5 (transpose + coalesced staging) = 234us;
// padim_main ~205us vs ~147us HBM floor. Remaining gap = RMW latency (VGPR=68
// -> only ~2-3 cov loads in flight) + long per-block serial chain. Changes:
//   - grid (PP, 2): each block does 96 cov rows in ONE pass (halved chain,
//     2x block parallelism; duplicate Et stage is L3-hit, ~free)
//   - __launch_bounds__(256,4): 128-VGPR cap -> ~8-10 cov loads in flight
//   - nontemporal loads on cov stream (read-once; keep L3 for Et)
//   - nontemporal stores on out_covs (write-once)

#define BB 32
#define CC 192
#define PP 3136
#define II (BB * CC)   // 6144
#define EPSV 0.01f

typedef float nat_float4 __attribute__((ext_vector_type(4)));

// ---------- Kernel 1: tiled transpose emb [II][PP] -> Et [PP][II] ----------
__global__ __launch_bounds__(256) void transpose_kernel(
    const float* __restrict__ emb, float* __restrict__ Et)
{
    __shared__ float tile[64][65];          // +1 pad: conflict-free col reads
    const int i0 = blockIdx.x * 64;         // 96 tiles over II
    const int p0 = blockIdx.y * 64;         // 49 tiles over PP
    const int t = threadIdx.x;
    const int tc = t & 63;                  // fast index (coalesced)
    const int tr4 = t >> 6;                 // 0..3

    #pragma unroll
    for (int k = 0; k < 16; ++k) {
        const int r = k * 4 + tr4;          // i-local row
        // nt load: emb never re-read; keep L3 capacity for Et
        tile[r][tc] = __builtin_nontemporal_load(&emb[(size_t)(i0 + r) * PP + (p0 + tc)]);
    }
    __syncthreads();
    #pragma unroll
    for (int k = 0; k < 16; ++k) {
        const int r = k * 4 + tr4;          // p-local row
        // normal store: Et wants to be L3-resident for kernel 2
        Et[(size_t)(p0 + r) * II + (i0 + tc)] = tile[tc][r];
    }
}

// ---------- Kernel 2: per-patch-slab SYRK + finalize ----------
__global__ __launch_bounds__(256, 4) void padim_main(
    const float* __restrict__ Et,     // [P][II] transposed embeddings
    const float* __restrict__ means,  // [P,C]
    const float* __restrict__ covs,   // [P,C,C]
    const int*   __restrict__ n_ptr,  // [1]
    float* __restrict__ out_means,    // [P,C]
    float* __restrict__ out_covs)     // [P,C,C]
{
    __shared__ __align__(16) float E[II];   // 24 KB, flat [b*CC + c]
    __shared__ __align__(16) float m[CC];

    const int p = blockIdx.x;
    const int slab = blockIdx.y;            // 0: rows 0..95, 1: rows 96..191
    const int t = threadIdx.x;

    const float n_new = (float)(n_ptr[0] + BB);       // 128
    const float inv_nnew = 1.0f / n_new;
    const float inv_nm1 = 1.0f / (n_new - 1.0f);      // 1/127

    // ---- Stage Et[p] -> LDS: 6 coalesced float4 per thread (L3-hit) ----
    {
        const float4* __restrict__ src = reinterpret_cast<const float4*>(Et + (size_t)p * II);
        float4* dst = reinterpret_cast<float4*>(E);
        #pragma unroll
        for (int k = 0; k < 6; ++k) dst[k * 256 + t] = src[k * 256 + t];
    }
    __syncthreads();

    // ---- Means (both slabs compute; slab 0 writes) ----
    if (t < CC) {
        float s = 0.0f;
        #pragma unroll
        for (int b = 0; b < BB; ++b) s += E[b * CC + t];
        const float mm = (means[(size_t)p * CC + t] + s) * inv_nnew;
        m[t] = mm;
        if (slab == 0) out_means[(size_t)p * CC + t] = mm;
    }
    __syncthreads();

    const int tx = t & 15;   // d: 3 groups of cols g*64 + tx*4
    const int ty = t >> 4;   // c: 6 rows within this slab's 96
    const int dbase0 = tx * 4;
    const int c0 = slab * 96 + ty * 6;

    const float* __restrict__ cov_p = covs + (size_t)p * CC * CC;
    float* __restrict__ out_p = out_covs + (size_t)p * CC * CC;

    float md[12];
    *reinterpret_cast<float4*>(&md[0]) = *reinterpret_cast<const float4*>(&m[dbase0]);
    *reinterpret_cast<float4*>(&md[4]) = *reinterpret_cast<const float4*>(&m[64 + dbase0]);
    *reinterpret_cast<float4*>(&md[8]) = *reinterpret_cast<const float4*>(&m[128 + dbase0]);

    float acc[6][12];
    #pragma unroll
    for (int i = 0; i < 6; ++i)
        #pragma unroll
        for (int j = 0; j < 12; ++j) acc[i][j] = 0.f;

    #pragma unroll 4
    for (int b = 0; b < BB; ++b) {
        const float* __restrict__ Eb = E + b * CC;
        float cs[6], ds[12];
        *reinterpret_cast<float4*>(&ds[0]) = *reinterpret_cast<const float4*>(&Eb[dbase0]);
        *reinterpret_cast<float4*>(&ds[4]) = *reinterpret_cast<const float4*>(&Eb[64 + dbase0]);
        *reinterpret_cast<float4*>(&ds[8]) = *reinterpret_cast<const float4*>(&Eb[128 + dbase0]);
        *reinterpret_cast<float2*>(&cs[0]) = *reinterpret_cast<const float2*>(&Eb[c0]);
        *reinterpret_cast<float2*>(&cs[2]) = *reinterpret_cast<const float2*>(&Eb[c0 + 2]);
        *reinterpret_cast<float2*>(&cs[4]) = *reinterpret_cast<const float2*>(&Eb[c0 + 4]);
        #pragma unroll
        for (int i = 0; i < 6; ++i)
            #pragma unroll
            for (int j = 0; j < 12; ++j)
                acc[i][j] = fmaf(cs[i], ds[j], acc[i][j]);
    }

    float mc[6];
    *reinterpret_cast<float2*>(&mc[0]) = *reinterpret_cast<const float2*>(&m[c0]);
    *reinterpret_cast<float2*>(&mc[2]) = *reinterpret_cast<const float2*>(&m[c0 + 2]);
    *reinterpret_cast<float2*>(&mc[4]) = *reinterpret_cast<const float2*>(&m[c0 + 4]);

    // ---- Fused finalize + cov RMW stream (nt in, nt out) ----
    #pragma unroll
    for (int i = 0; i < 6; ++i) {
        const int c = c0 + i;
        const size_t row = (size_t)c * CC;
        const float nmc = n_new * mc[i];
        #pragma unroll
        for (int g = 0; g < 3; ++g) {
            const int db = g * 64 + dbase0;
            const nat_float4 cin = __builtin_nontemporal_load(
                reinterpret_cast<const nat_float4*>(&cov_p[row + db]));
            nat_float4 o;
            o.x = (cin.x + acc[i][g*4+0] - nmc * md[g*4+0]) * inv_nm1;
            o.y = (cin.y + acc[i][g*4+1] - nmc * md[g*4+1]) * inv_nm1;
            o.z = (cin.z + acc[i][g*4+2] - nmc * md[g*4+2]) * inv_nm1;
            o.w = (cin.w + acc[i][g*4+3] - nmc * md[g*4+3]) * inv_nm1;
            const int dd = c - db;   // diagonal hits when 0 <= dd < 4
            if (dd == 0) o.x += EPSV;
            if (dd == 1) o.y += EPSV;
            if (dd == 2) o.z += EPSV;
            if (dd == 3) o.w += EPSV;
            __builtin_nontemporal_store(o, reinterpret_cast<nat_float4*>(&out_p[row + db]));
        }
    }
}

// ---------- Fallback (ws too small): single-kernel with direct gather ----
__global__ __launch_bounds__(256, 3) void padim_fallback(
    const float* __restrict__ emb, const float* __restrict__ means,
    const float* __restrict__ covs, const int* __restrict__ n_ptr,
    float* __restrict__ out_means, float* __restrict__ out_covs)
{
    __shared__ __align__(16) float E[II];
    __shared__ __align__(16) float m[CC];
    const int bid = blockIdx.x;
    const int p = (bid & 7) * (PP / 8) + (bid >> 3);
    const int t = threadIdx.x;
    const float n_new = (float)(n_ptr[0] + BB);
    const float inv_nnew = 1.0f / n_new;
    const float inv_nm1 = 1.0f / (n_new - 1.0f);
    #pragma unroll
    for (int k = 0; k < II / 256; ++k) {
        const int i = t + k * 256;
        E[i] = emb[(size_t)i * PP + p];
    }
    __syncthreads();
    if (t < CC) {
        float s = 0.0f;
        #pragma unroll
        for (int b = 0; b < BB; ++b) s += E[b * CC + t];
        const float mm = (means[(size_t)p * CC + t] + s) * inv_nnew;
        m[t] = mm;
        out_means[(size_t)p * CC + t] = mm;
    }
    __syncthreads();
    const int tx = t & 15, ty = t >> 4;
    const int dbase0 = tx * 4;
    const float* __restrict__ cov_p = covs + (size_t)p * CC * CC;
    float* __restrict__ out_p = out_covs + (size_t)p * CC * CC;
    float md[12];
    *reinterpret_cast<float4*>(&md[0]) = *reinterpret_cast<const float4*>(&m[dbase0]);
    *reinterpret_cast<float4*>(&md[4]) = *reinterpret_cast<const float4*>(&m[64 + dbase0]);
    *reinterpret_cast<float4*>(&md[8]) = *reinterpret_cast<const float4*>(&m[128 + dbase0]);
    #pragma unroll
    for (int pass = 0; pass < 2; ++pass) {
        const int c0 = pass * 96 + ty * 6;
        float acc[6][12];
        #pragma unroll
        for (int i = 0; i < 6; ++i)
            #pragma unroll
            for (int j = 0; j < 12; ++j) acc[i][j] = 0.f;
        #pragma unroll 4
        for (int b = 0; b < BB; ++b) {
            const float* __restrict__ Eb = E + b * CC;
            float cs[6], ds[12];
            *reinterpret_cast<float4*>(&ds[0]) = *reinterpret_cast<const float4*>(&Eb[dbase0]);
            *reinterpret_cast<float4*>(&ds[4]) = *reinterpret_cast<const float4*>(&Eb[64 + dbase0]);
            *reinterpret_cast<float4*>(&ds[8]) = *reinterpret_cast<const float4*>(&Eb[128 + dbase0]);
            *reinterpret_cast<float2*>(&cs[0]) = *reinterpret_cast<const float2*>(&Eb[c0]);
            *reinterpret_cast<float2*>(&cs[2]) = *reinterpret_cast<const float2*>(&Eb[c0 + 2]);
            *reinterpret_cast<float2*>(&cs[4]) = *reinterpret_cast<const float2*>(&Eb[c0 + 4]);
            #pragma unroll
            for (int i = 0; i < 6; ++i)
                #pragma unroll
                for (int j = 0; j < 12; ++j)
                    acc[i][j] = fmaf(cs[i], ds[j], acc[i][j]);
        }
        float mc[6];
        *reinterpret_cast<float2*>(&mc[0]) = *reinterpret_cast<const float2*>(&m[c0]);
        *reinterpret_cast<float2*>(&mc[2]) = *reinterpret_cast<const float2*>(&m[c0 + 2]);
        *reinterpret_cast<float2*>(&mc[4]) = *reinterpret_cast<const float2*>(&m[c0 + 4]);
        #pragma unroll
        for (int i = 0; i < 6; ++i) {
            const int c = c0 + i;
            const size_t row = (size_t)c * CC;
            const float nmc = n_new * mc[i];
            #pragma unroll
            for (int g = 0; g < 3; ++g) {
                const int db = g * 64 + dbase0;
                const float4 cin = *reinterpret_cast<const float4*>(&cov_p[row + db]);
                float4 o;
                o.x = (cin.x + acc[i][g*4+0] - nmc * md[g*4+0]) * inv_nm1;
                o.y = (cin.y + acc[i][g*4+1] - nmc * md[g*4+1]) * inv_nm1;
                o.z = (cin.z + acc[i][g*4+2] - nmc * md[g*4+2]) * inv_nm1;
                o.w = (cin.w + acc[i][g*4+3] - nmc * md[g*4+3]) * inv_nm1;
                const int dd = c - db;
                if (dd == 0) o.x += EPSV;
                if (dd == 1) o.y += EPSV;
                if (dd == 2) o.z += EPSV;
                if (dd == 3) o.w += EPSV;
                *reinterpret_cast<float4*>(&out_p[row + db]) = o;
            }
        }
    }
}

extern "C" void kernel_launch(void* const* d_in, const int* in_sizes, int n_in,
                              void* d_out, int out_size, void* d_ws, size_t ws_size,
                              hipStream_t stream) {
    const float* emb   = (const float*)d_in[0];
    const float* means = (const float*)d_in[1];
    const float* covs  = (const float*)d_in[2];
    const int*   n_ptr = (const int*)d_in[3];

    float* out_means = (float*)d_out;                      // [P,C]
    float* out_covs  = (float*)d_out + (size_t)PP * CC;    // [P,C,C]

    const size_t et_bytes = (size_t)PP * II * sizeof(float);   // 77.1 MB
    if (ws_size >= et_bytes) {
        float* Et = (float*)d_ws;
        hipLaunchKernelGGL(transpose_kernel, dim3(II / 64, PP / 64), dim3(256),
                           0, stream, emb, Et);
        hipLaunchKernelGGL(padim_main, dim3(PP, 2), dim3(256), 0, stream,
                           Et, means, covs, n_ptr, out_means, out_covs);
    } else {
        hipLaunchKernelGGL(padim_fallback, dim3(PP), dim3(256), 0, stream,
                           emb, means, covs, n_ptr, out_means, out_covs);
    }
}